// Round 1
// baseline (32620.972 us; speedup 1.0000x reference)
//
#include <hip/hip_runtime.h>
#include <math.h>

// Model_13348758356240: 20-step LSTM decoder w/ spatial attention, greedy argmax feedback.
// Round 1: pure-fp32 correctness baseline. All GEMMs on VALU with LDS tiles.
// ws layout (floats): sp_proj | xh | gates | h | m | hg | hgp | a | tok

#define B_   128
#define L_   49
#define D_   2048
#define H_   2048
#define E_   512
#define KA_  512
#define V_   10000
#define T_   20
#define ED_  2560
#define KT_  4608
#define H4_  8192

// ---------------- generic tiled GEMM ----------------
// C[M,N] = act(A @ op(B) + bias1 + bias2)
// TRANSB=1: B is [N,K] row-major (C = A @ B^T); dual weight pointers split at ksplit.
// TRANSB=0: B is [K,N] row-major (C = A @ B).
// 128 threads, tile 64(M) x 64(N), BK=16, micro-tile 4x8 per thread.
template<int TRANSB, int ACT>
__global__ __launch_bounds__(128)
void gemm_f32(const float* __restrict__ A, int lda,
              const float* __restrict__ B1, int ldb1,
              const float* __restrict__ B2, int ldb2, int ksplit,
              const float* __restrict__ bias1, const float* __restrict__ bias2,
              float* __restrict__ C, long ldc, int N, int Ktot)
{
  __shared__ float As[16][68];
  __shared__ float Bs[16][68];
  const int tid = threadIdx.x;
  const int tx = tid & 7;        // 8 col-groups of 8
  const int ty = tid >> 3;       // 16 row-groups of 4
  const int n0 = blockIdx.x * 64;
  const int m0 = blockIdx.y * 64;
  const int kkA = tid & 15;      // k within tile for staging
  const int r0  = tid >> 4;      // 0..7 row/colgroup for staging

  float acc[4][8];
#pragma unroll
  for (int i = 0; i < 4; ++i)
#pragma unroll
    for (int j = 0; j < 8; ++j) acc[i][j] = 0.f;

  for (int k0 = 0; k0 < Ktot; k0 += 16) {
    // stage A tile: rows m0..m0+63, k = k0..k0+15  (M always multiple of 64)
#pragma unroll
    for (int i = 0; i < 8; ++i) {
      As[kkA][r0 + 8*i] = A[(long)(m0 + r0 + 8*i) * lda + (k0 + kkA)];
    }
    if (TRANSB) {
      const int kg = k0 + kkA;
      if (kg < ksplit) {
#pragma unroll
        for (int i = 0; i < 8; ++i) {
          const int n = n0 + r0 + 8*i;
          Bs[kkA][r0 + 8*i] = (n < N) ? B1[(long)n * ldb1 + kg] : 0.f;
        }
      } else {
        const int kb = kg - ksplit;
#pragma unroll
        for (int i = 0; i < 8; ++i) {
          const int n = n0 + r0 + 8*i;
          Bs[kkA][r0 + 8*i] = (n < N) ? B2[(long)n * ldb2 + kb] : 0.f;
        }
      }
    } else {
      const int c = tid & 63, kh = tid >> 6; // kh 0..1
#pragma unroll
      for (int i = 0; i < 8; ++i) {
        const int kr = kh + 2*i;
        const int n = n0 + c;
        Bs[kr][c] = (n < N) ? B1[(long)(k0 + kr) * ldb1 + n] : 0.f;
      }
    }
    __syncthreads();
#pragma unroll
    for (int kk = 0; kk < 16; ++kk) {
      const float4 a4 = *(const float4*)&As[kk][ty*4];
      const float4 b0 = *(const float4*)&Bs[kk][tx*8];
      const float4 b1 = *(const float4*)&Bs[kk][tx*8 + 4];
      const float av[4] = {a4.x, a4.y, a4.z, a4.w};
      const float bv[8] = {b0.x, b0.y, b0.z, b0.w, b1.x, b1.y, b1.z, b1.w};
#pragma unroll
      for (int i = 0; i < 4; ++i)
#pragma unroll
        for (int j = 0; j < 8; ++j)
          acc[i][j] = fmaf(av[i], bv[j], acc[i][j]);
    }
    __syncthreads();
  }
#pragma unroll
  for (int i = 0; i < 4; ++i) {
    const int m = m0 + ty*4 + i;
#pragma unroll
    for (int j = 0; j < 8; ++j) {
      const int n = n0 + tx*8 + j;
      if (n < N) {
        float v = acc[i][j];
        if (bias1) v += bias1[n];
        if (bias2) v += bias2[n];
        if (ACT == 1) v = tanhf(v);
        C[(long)m * ldc + n] = v;
      }
    }
  }
}

// ---------------- small kernels ----------------
__global__ void init_tok_k(int* tok) {
  if (threadIdx.x < B_) tok[threadIdx.x] = 1; // START_IDX
}

__global__ void gather_xh_k(const float* __restrict__ embed, const float* __restrict__ global_,
                            const float* __restrict__ h, const int* __restrict__ tok,
                            float* __restrict__ xh)
{
  const int b = blockIdx.x, tid = threadIdx.x;
  const int tk = tok[b];
  const float* e = embed + (long)tk * E_;
  float* row = xh + (long)b * KT_;
  for (int i = tid; i < E_; i += 256)  row[i] = e[i];
  for (int i = tid; i < D_; i += 256)  row[E_ + i] = global_[(long)b * D_ + i];
  for (int i = tid; i < H_; i += 256)  row[ED_ + i] = h[(long)b * H_ + i];
}

__global__ void lstm_k(const float* __restrict__ gates, float* __restrict__ h, float* __restrict__ m)
{
  const int idx = blockIdx.x * 256 + threadIdx.x;   // 0 .. B*H-1
  const int b = idx >> 11, n = idx & (H_ - 1);
  const float* g = gates + (long)b * H4_;
  const float ig = g[n];
  const float fg = g[n + H_];
  const float gg = g[n + 2*H_];
  const float og = g[n + 3*H_];
  const float si = 1.f / (1.f + expf(-ig));
  const float sf = 1.f / (1.f + expf(-fg));
  const float so = 1.f / (1.f + expf(-og));
  const float mn = sf * m[idx] + si * tanhf(gg);
  const float hn = so * tanhf(mn);
  m[idx] = mn;
  h[idx] = hn;
}

// split-K partials for hg = h @ W_g : grid (8 n-blocks, 16 k-chunks), 256 thr
__global__ __launch_bounds__(256)
void hg_partial_k(const float* __restrict__ h, const float* __restrict__ Wg,
                  float* __restrict__ hgp)
{
  const int nb = blockIdx.x;   // 0..7
  const int kc = blockIdx.y;   // 0..15
  const int tid = threadIdx.x;
  const int tx = tid & 15, ty = tid >> 4;
  __shared__ float As[16][132];
  __shared__ float Bs[16][68];
  float acc[8][4];
#pragma unroll
  for (int i = 0; i < 8; ++i)
#pragma unroll
    for (int j = 0; j < 4; ++j) acc[i][j] = 0.f;

  const int kbase = kc * 128;
  const int kkA = tid & 15, r0 = tid >> 4;   // staging A
  const int c = tid & 63, kh = tid >> 6;     // staging B
  for (int kt = 0; kt < 8; ++kt) {
    const int k0 = kbase + kt * 16;
#pragma unroll
    for (int i = 0; i < 8; ++i)
      As[kkA][r0 + 16*i] = h[(long)(r0 + 16*i) * H_ + k0 + kkA];
#pragma unroll
    for (int i = 0; i < 4; ++i)
      Bs[kh + 4*i][c] = Wg[(long)(k0 + kh + 4*i) * KA_ + nb*64 + c];
    __syncthreads();
#pragma unroll
    for (int kk = 0; kk < 16; ++kk) {
      const float4 b4 = *(const float4*)&Bs[kk][tx*4];
      const float4 a0 = *(const float4*)&As[kk][ty*8];
      const float4 a1 = *(const float4*)&As[kk][ty*8 + 4];
      const float av[8] = {a0.x,a0.y,a0.z,a0.w,a1.x,a1.y,a1.z,a1.w};
      const float bv[4] = {b4.x,b4.y,b4.z,b4.w};
#pragma unroll
      for (int i = 0; i < 8; ++i)
#pragma unroll
        for (int j = 0; j < 4; ++j)
          acc[i][j] = fmaf(av[i], bv[j], acc[i][j]);
    }
    __syncthreads();
  }
#pragma unroll
  for (int i = 0; i < 8; ++i) {
    const int mrow = ty*8 + i;
#pragma unroll
    for (int j = 0; j < 4; ++j) {
      const int n = nb*64 + tx*4 + j;
      hgp[((long)kc * B_ + mrow) * KA_ + n] = acc[i][j];
    }
  }
}

__global__ void hg_reduce_k(const float* __restrict__ hgp, float* __restrict__ hg)
{
  const int i = blockIdx.x * 256 + threadIdx.x;  // 0 .. B*KA-1
  float s = 0.f;
#pragma unroll
  for (int kc = 0; kc < 16; ++kc) s += hgp[(long)kc * (B_*KA_) + i];
  hg[i] = s;
}

// per-b: z = w_h . tanh(sp_proj + hg), softmax over L, a = h + sum_l alpha_l * spatial[l]
__global__ __launch_bounds__(256)
void attn_k(const float* __restrict__ sp_proj, const float* __restrict__ hg,
            const float* __restrict__ w_h, const float* __restrict__ spatial,
            const float* __restrict__ h, float* __restrict__ a)
{
  const int b = blockIdx.x, tid = threadIdx.x;
  const int lane = tid & 63, wv = tid >> 6;
  __shared__ float hgs[KA_];
  __shared__ float whs[KA_];
  __shared__ float zs[L_];
  __shared__ float alph[L_];
  for (int i = tid; i < KA_; i += 256) { hgs[i] = hg[(long)b*KA_ + i]; whs[i] = w_h[i]; }
  __syncthreads();
  for (int l = wv; l < L_; l += 4) {
    const float* sp = sp_proj + ((long)b * L_ + l) * KA_;
    float s = 0.f;
    for (int k = lane; k < KA_; k += 64) s += whs[k] * tanhf(sp[k] + hgs[k]);
#pragma unroll
    for (int off = 32; off > 0; off >>= 1) s += __shfl_down(s, off);
    if (lane == 0) zs[l] = s;
  }
  __syncthreads();
  if (wv == 0) {
    float v = (lane < L_) ? zs[lane] : -INFINITY;
    float mx = v;
#pragma unroll
    for (int off = 32; off > 0; off >>= 1) mx = fmaxf(mx, __shfl_xor(mx, off));
    float e = (lane < L_) ? expf(v - mx) : 0.f;
    float sum = e;
#pragma unroll
    for (int off = 32; off > 0; off >>= 1) sum += __shfl_xor(sum, off);
    if (lane < L_) alph[lane] = e / sum;
  }
  __syncthreads();
  for (int d = tid; d < D_; d += 256) {
    float acc = h[(long)b * H_ + d];
    const float* spb = spatial + (long)b * L_ * D_ + d;
#pragma unroll 7
    for (int l = 0; l < L_; ++l) acc += alph[l] * spb[(long)l * D_];
    a[(long)b * D_ + d] = acc;
  }
}

// per-b argmax over V logits; first index wins ties; writes int tok + float token output
__global__ __launch_bounds__(256)
void argmax_k(const float* __restrict__ logits, long row_stride,
              int* __restrict__ tok, float* __restrict__ tokout)
{
  const int b = blockIdx.x, tid = threadIdx.x;
  const float* row = logits + (long)b * row_stride;
  float bv = -INFINITY; int bi = 0x7fffffff;
  for (int k = tid; k < V_; k += 256) {
    const float v = row[k];
    if (v > bv) { bv = v; bi = k; }   // ascending scan keeps lowest index on ties
  }
  __shared__ float sv[256];
  __shared__ int   si[256];
  sv[tid] = bv; si[tid] = bi;
  __syncthreads();
  for (int s = 128; s > 0; s >>= 1) {
    if (tid < s) {
      const float ov = sv[tid + s]; const int oi = si[tid + s];
      if (ov > sv[tid] || (ov == sv[tid] && oi < si[tid])) { sv[tid] = ov; si[tid] = oi; }
    }
    __syncthreads();
  }
  if (tid == 0) { tok[b] = si[0]; tokout[(long)b * T_] = (float)si[0]; }
}

// ---------------- host ----------------
extern "C" void kernel_launch(void* const* d_in, const int* in_sizes, int n_in,
                              void* d_out, int out_size, void* d_ws, size_t ws_size,
                              hipStream_t stream)
{
  const float* spatial  = (const float*)d_in[0];
  const float* global_  = (const float*)d_in[1];
  const float* embed    = (const float*)d_in[2];
  const float* W_ih     = (const float*)d_in[3];
  const float* W_hh     = (const float*)d_in[4];
  const float* b_ih     = (const float*)d_in[5];
  const float* b_hh     = (const float*)d_in[6];
  const float* W_v      = (const float*)d_in[7];
  const float* W_g      = (const float*)d_in[8];
  const float* w_h      = (const float*)d_in[9];
  const float* W_p_w    = (const float*)d_in[10];
  const float* W_p_b    = (const float*)d_in[11];
  const float* W_init_h = (const float*)d_in[12];
  const float* W_init_m = (const float*)d_in[13];
  float* out = (float*)d_out;

  // ws layout
  float* ws    = (float*)d_ws;
  float* sp    = ws;                    // 128*49*512   = 3,211,264
  float* xh    = sp    + 3211264;       // 128*4608     =   589,824
  float* gates = xh    + 589824;        // 128*8192     = 1,048,576
  float* h     = gates + 1048576;       // 128*2048     =   262,144
  float* m     = h     + 262144;        // 128*2048     =   262,144
  float* hg    = m     + 262144;        // 128*512      =    65,536
  float* hgp   = hg    + 65536;         // 16*128*512   = 1,048,576
  float* a     = hgp   + 1048576;       // 128*2048     =   262,144
  int*   tok   = (int*)(a + 262144);    // 128
  const size_t needed = (size_t)(6750336) * 4;
  if (ws_size < needed) return;  // cannot run safely

  float* tokout = out + (long)B_ * T_ * V_;  // tokens section, [b][t] as float

  init_tok_k<<<1, 128, 0, stream>>>(tok);

  // h0 = tanh(global_ @ W_init_h), m0 = tanh(global_ @ W_init_m)   (NN)
  gemm_f32<0,1><<<dim3(H_/64, B_/64), 128, 0, stream>>>(
      global_, D_, W_init_h, H_, nullptr, 0, D_, nullptr, nullptr, h, H_, H_, D_);
  gemm_f32<0,1><<<dim3(H_/64, B_/64), 128, 0, stream>>>(
      global_, D_, W_init_m, H_, nullptr, 0, D_, nullptr, nullptr, m, H_, H_, D_);
  // spatial_proj = spatial @ W_v   (NN)  [6272,2048]x[2048,512]
  gemm_f32<0,0><<<dim3(KA_/64, (B_*L_)/64), 128, 0, stream>>>(
      spatial, D_, W_v, KA_, nullptr, 0, D_, nullptr, nullptr, sp, KA_, KA_, D_);

  for (int t = 0; t < T_; ++t) {
    gather_xh_k<<<B_, 256, 0, stream>>>(embed, global_, h, tok, xh);
    // gates = xh @ [W_ih|W_hh]^T + b_ih + b_hh   (NT, dual weights split at k=2560)
    gemm_f32<1,0><<<dim3(H4_/64, B_/64), 128, 0, stream>>>(
        xh, KT_, W_ih, ED_, W_hh, H_, ED_, b_ih, b_hh, gates, H4_, H4_, KT_);
    lstm_k<<<(B_*H_)/256, 256, 0, stream>>>(gates, h, m);
    hg_partial_k<<<dim3(8, 16), 256, 0, stream>>>(h, W_g, hgp);
    hg_reduce_k<<<(B_*KA_)/256, 256, 0, stream>>>(hgp, hg);
    attn_k<<<B_, 256, 0, stream>>>(sp, hg, w_h, spatial, h, a);
    // logits = a @ W_p_w^T + W_p_b  -> d_out[b][t][:]   (NT)
    gemm_f32<1,0><<<dim3((V_+63)/64, B_/64), 128, 0, stream>>>(
        a, H_, W_p_w, H_, nullptr, 0, H_, W_p_b, nullptr,
        out + (long)t * V_, (long)T_ * V_, V_, H_);
    argmax_k<<<B_, 256, 0, stream>>>(out + (long)t * V_, (long)T_ * V_, tok, tokout + t);
  }
}

// Round 2
// 6699.049 us; speedup vs baseline: 4.8695x; 4.8695x over previous
//
#include <hip/hip_runtime.h>
#include <math.h>

// Model_13348758356240 — R2: split-bf16 MFMA GEMMs (3-pass hi/lo, ~fp32 accuracy),
// direct-from-global fragments (zero LDS), split-K + fused reduce epilogues.

typedef __attribute__((ext_vector_type(8))) short bf16x8;
typedef __attribute__((ext_vector_type(4))) float f32x4;

#define B_ 128
#define L_ 49
#define D_ 2048
#define H_ 2048
#define E_ 512
#define KA_ 512
#define V_ 10000
#define T_ 20
#define ED_ 2560
#define KT_ 4608
#define H4_ 8192
#define VP_ 10112   // padded V (79*128) for logits partials

__device__ __forceinline__ void split1(float x, short* hi, short* lo){
  unsigned u = __float_as_uint(x);
  *hi = (short)(u >> 16);
  float r = x - __uint_as_float(u & 0xffff0000u);
  *lo = (short)(__float_as_uint(r) >> 16);
}
__device__ __forceinline__ void split8(float4 a, float4 b, bf16x8& h, bf16x8& l){
  float xs[8] = {a.x,a.y,a.z,a.w,b.x,b.y,b.z,b.w};
#pragma unroll
  for (int i=0;i<8;++i){
    unsigned u = __float_as_uint(xs[i]);
    h[i] = (short)(u>>16);
    float r = xs[i] - __uint_as_float(u & 0xffff0000u);
    l[i] = (short)(__float_as_uint(r)>>16);
  }
}

// ---------------- MFMA GEMM: C_partial = A @ W^T over a K-slice ----------------
// A: [Mtot,K] as bf16 hi/lo arrays (or fp32 if AF32, split on the fly).
// W: fp32 [N,K] row-major (NT); optional dual weight W2 spliced at k=ksplit.
// Each wave: 128(M) x 32(N). Block: 4 waves = 128x128 N-span. Grid: (nb, S, mb).
// Split-bf16: acc += Ah*Wh + Ah*Wl + Al*Wh  (fp32 MFMA accumulators).
template<bool AF32>
__global__ __launch_bounds__(256)
void gemm_mfma(const void* Ahv, const void* Alv, int lda,
               const float* __restrict__ W1, int ldw1,
               const float* __restrict__ W2, int ldw2, int ksplit,
               float* __restrict__ Cp, int Mtot, int Np, int Nvalid, int k_len)
{
  const int tid = threadIdx.x;
  const int wid = tid >> 6, lane = tid & 63;
  const int lr = lane & 15, lg = lane >> 4;
  const int m0 = blockIdx.z * 128;
  const int nw = blockIdx.x * 128 + wid * 32;
  const int kb = blockIdx.y * k_len;

  int rowA = nw + lr;       if (rowA >= Nvalid) rowA = Nvalid - 1;
  int rowB = nw + 16 + lr;  if (rowB >= Nvalid) rowB = Nvalid - 1;

  f32x4 acc[8][2];
#pragma unroll
  for (int i=0;i<8;++i){
#pragma unroll
    for (int r=0;r<4;++r){ acc[i][0][r] = 0.f; acc[i][1][r] = 0.f; }
  }

  for (int kk = 0; kk < k_len; kk += 32) {
    const int kg = kb + kk;
    const float *pA, *pB;
    if (W2 && kg >= ksplit) {
      pA = W2 + (long)rowA*ldw2 + (kg - ksplit) + 8*lg;
      pB = W2 + (long)rowB*ldw2 + (kg - ksplit) + 8*lg;
    } else {
      pA = W1 + (long)rowA*ldw1 + kg + 8*lg;
      pB = W1 + (long)rowB*ldw1 + kg + 8*lg;
    }
    bf16x8 whA, wlA, whB, wlB;
    split8(*(const float4*)pA, *(const float4*)(pA+4), whA, wlA);
    split8(*(const float4*)pB, *(const float4*)(pB+4), whB, wlB);

    bf16x8 ah[8], al[8];
    if constexpr (AF32) {
      const float* Af = (const float*)Ahv;
#pragma unroll
      for (int mt=0; mt<8; ++mt){
        const float* ap = Af + (long)(m0 + mt*16 + lr)*lda + kg + 8*lg;
        split8(*(const float4*)ap, *(const float4*)(ap+4), ah[mt], al[mt]);
      }
    } else {
      const short* Ah = (const short*)Ahv;
      const short* Al = (const short*)Alv;
#pragma unroll
      for (int mt=0; mt<8; ++mt){
        const long off = (long)(m0 + mt*16 + lr)*lda + kg + 8*lg;
        ah[mt] = *(const bf16x8*)(Ah + off);
        al[mt] = *(const bf16x8*)(Al + off);
      }
    }
#pragma unroll
    for (int mt=0; mt<8; ++mt){
      acc[mt][0] = __builtin_amdgcn_mfma_f32_16x16x32_bf16(ah[mt], whA, acc[mt][0], 0,0,0);
      acc[mt][1] = __builtin_amdgcn_mfma_f32_16x16x32_bf16(ah[mt], whB, acc[mt][1], 0,0,0);
      acc[mt][0] = __builtin_amdgcn_mfma_f32_16x16x32_bf16(ah[mt], wlA, acc[mt][0], 0,0,0);
      acc[mt][1] = __builtin_amdgcn_mfma_f32_16x16x32_bf16(ah[mt], wlB, acc[mt][1], 0,0,0);
      acc[mt][0] = __builtin_amdgcn_mfma_f32_16x16x32_bf16(al[mt], whA, acc[mt][0], 0,0,0);
      acc[mt][1] = __builtin_amdgcn_mfma_f32_16x16x32_bf16(al[mt], whB, acc[mt][1], 0,0,0);
    }
  }

  const long srow = (long)blockIdx.y * Mtot + m0;
#pragma unroll
  for (int mt=0; mt<8; ++mt){
#pragma unroll
    for (int nt=0; nt<2; ++nt){
      const int col = nw + nt*16 + lr;
#pragma unroll
      for (int r=0; r<4; ++r){
        Cp[(srow + mt*16 + 4*lg + r)*Np + col] = acc[mt][nt][r];
      }
    }
  }
}

// ---------------- fp32 tiled transpose (R,C multiples of 64) ----------------
__global__ __launch_bounds__(256)
void transpose_f32(const float* __restrict__ in, int R, int C, float* __restrict__ out)
{
  __shared__ float t[64][65];
  const int tid = threadIdx.x;
  const int c0 = blockIdx.x * 64, r0 = blockIdx.y * 64;
  const int lx = tid & 63, ly = tid >> 6;
#pragma unroll
  for (int i = 0; i < 16; ++i)
    t[ly + 4*i][lx] = in[(long)(r0 + ly + 4*i) * C + c0 + lx];
  __syncthreads();
#pragma unroll
  for (int i = 0; i < 16; ++i)
    out[(long)(c0 + ly + 4*i) * R + r0 + lx] = t[lx][ly + 4*i];
}

// ---------------- small kernels ----------------
__global__ void init_tok_k(int* tok) {
  if (threadIdx.x < B_) tok[threadIdx.x] = 1; // START_IDX
}

// reduce S=4 partials + tanh; optional bf16 split outputs
__global__ __launch_bounds__(256)
void reduce_tanh_k(const float* __restrict__ gp, float* __restrict__ out,
                   short* __restrict__ ohi, short* __restrict__ olo)
{
  const int idx = blockIdx.x * 256 + threadIdx.x;  // 0 .. B*H-1
  float s = 0.f;
#pragma unroll
  for (int sl = 0; sl < 4; ++sl) s += gp[(long)sl * (B_*H_) + idx];
  s = tanhf(s);
  out[idx] = s;
  if (ohi) split1(s, &ohi[idx], &olo[idx]);
}

// gather xh = [embed[tok] | global_ | h] into bf16 hi/lo
__global__ void gather_xh_k(const float* __restrict__ embed, const float* __restrict__ global_,
                            const float* __restrict__ h, const short* __restrict__ h_hi,
                            const short* __restrict__ h_lo, const int* __restrict__ tok,
                            short* __restrict__ xh_hi, short* __restrict__ xh_lo)
{
  const int b = blockIdx.x, tid = threadIdx.x;
  const int tk = tok[b];
  short* rh = xh_hi + (long)b * KT_;
  short* rl = xh_lo + (long)b * KT_;
  const float* e = embed + (long)tk * E_;
  for (int i = tid; i < E_; i += 256) split1(e[i], &rh[i], &rl[i]);
  for (int i = tid; i < D_; i += 256) split1(global_[(long)b * D_ + i], &rh[E_ + i], &rl[E_ + i]);
  for (int i = tid; i < H_; i += 256) { rh[ED_ + i] = h_hi[(long)b * H_ + i]; rl[ED_ + i] = h_lo[(long)b * H_ + i]; }
}

// reduce gates partials (S=8) + biases + LSTM cell; writes h, m, h splits
__global__ __launch_bounds__(256)
void lstm_reduce_k(const float* __restrict__ gp, const float* __restrict__ b_ih,
                   const float* __restrict__ b_hh, float* __restrict__ h, float* __restrict__ m,
                   short* __restrict__ h_hi, short* __restrict__ h_lo)
{
  const int idx = blockIdx.x * 256 + threadIdx.x;  // 0 .. B*H-1
  const int b = idx >> 11, n = idx & (H_ - 1);
  float g[4];
#pragma unroll
  for (int j = 0; j < 4; ++j) {
    float s = b_ih[j*H_ + n] + b_hh[j*H_ + n];
#pragma unroll
    for (int sl = 0; sl < 8; ++sl) s += gp[((long)sl * B_ + b) * H4_ + j*H_ + n];
    g[j] = s;
  }
  const float si = 1.f / (1.f + expf(-g[0]));
  const float sf = 1.f / (1.f + expf(-g[1]));
  const float gg = tanhf(g[2]);
  const float so = 1.f / (1.f + expf(-g[3]));
  const float mn = sf * m[idx] + si * gg;
  const float hn = so * tanhf(mn);
  m[idx] = mn; h[idx] = hn;
  split1(hn, &h_hi[idx], &h_lo[idx]);
}

// per-(b, half-D): reduce hg partials, z = w_h.tanh(sp+hg), softmax, a = h + alpha@spatial
__global__ __launch_bounds__(256)
void attn_k(const float* __restrict__ sp_proj, const float* __restrict__ hgp,
            const float* __restrict__ w_h, const float* __restrict__ spatial,
            const float* __restrict__ h, float* __restrict__ a,
            short* __restrict__ a_hi, short* __restrict__ a_lo)
{
  const int b = blockIdx.x, half = blockIdx.y, tid = threadIdx.x;
  const int lane = tid & 63, wv = tid >> 6;
  __shared__ float hgs[KA_];
  __shared__ float whs[KA_];
  __shared__ float zs[L_];
  __shared__ float alph[L_];
  for (int i = tid; i < KA_; i += 256) {
    float s = 0.f;
#pragma unroll
    for (int sl = 0; sl < 16; ++sl) s += hgp[((long)sl * B_ + b) * KA_ + i];
    hgs[i] = s; whs[i] = w_h[i];
  }
  __syncthreads();
  for (int l = wv; l < L_; l += 4) {
    const float* sp = sp_proj + ((long)b * L_ + l) * KA_;
    float s = 0.f;
    for (int k = lane; k < KA_; k += 64) s += whs[k] * tanhf(sp[k] + hgs[k]);
#pragma unroll
    for (int off = 32; off > 0; off >>= 1) s += __shfl_down(s, off);
    if (lane == 0) zs[l] = s;
  }
  __syncthreads();
  if (wv == 0) {
    float v = (lane < L_) ? zs[lane] : -INFINITY;
    float mx = v;
#pragma unroll
    for (int off = 32; off > 0; off >>= 1) mx = fmaxf(mx, __shfl_xor(mx, off));
    float e = (lane < L_) ? expf(v - mx) : 0.f;
    float sum = e;
#pragma unroll
    for (int off = 32; off > 0; off >>= 1) sum += __shfl_xor(sum, off);
    if (lane < L_) alph[lane] = e / sum;
  }
  __syncthreads();
  const int d0 = half * (D_/2);
  for (int d = d0 + tid; d < d0 + D_/2; d += 256) {
    float acc = h[(long)b * H_ + d];
    const float* spb = spatial + (long)b * L_ * D_ + d;
#pragma unroll 7
    for (int l = 0; l < L_; ++l) acc += alph[l] * spb[(long)l * D_];
    const long o = (long)b * D_ + d;
    a[o] = acc;
    split1(acc, &a_hi[o], &a_lo[o]);
  }
}

// per-b: reduce logits partials (S=4, padded VP_) + bias -> out, then argmax
__global__ __launch_bounds__(256)
void logits_argmax_k(const float* __restrict__ lp, const float* __restrict__ bias,
                     float* __restrict__ outL, int* __restrict__ tok,
                     float* __restrict__ tokout)
{
  const int b = blockIdx.x, tid = threadIdx.x;
  float bv = -INFINITY; int bi = 0x7fffffff;
  for (int j = tid; j < V_; j += 256) {
    float v = bias[j];
#pragma unroll
    for (int sl = 0; sl < 4; ++sl) v += lp[((long)sl * B_ + b) * VP_ + j];
    outL[(long)b * (T_*V_) + j] = v;
    if (v > bv) { bv = v; bi = j; }
  }
  __shared__ float sv[256];
  __shared__ int   si[256];
  sv[tid] = bv; si[tid] = bi;
  __syncthreads();
  for (int s = 128; s > 0; s >>= 1) {
    if (tid < s) {
      const float ov = sv[tid + s]; const int oi = si[tid + s];
      if (ov > sv[tid] || (ov == sv[tid] && oi < si[tid])) { sv[tid] = ov; si[tid] = oi; }
    }
    __syncthreads();
  }
  if (tid == 0) { tok[b] = si[0]; tokout[(long)b * T_] = (float)si[0]; }
}

// ---------------- host ----------------
extern "C" void kernel_launch(void* const* d_in, const int* in_sizes, int n_in,
                              void* d_out, int out_size, void* d_ws, size_t ws_size,
                              hipStream_t stream)
{
  const float* spatial  = (const float*)d_in[0];
  const float* global_  = (const float*)d_in[1];
  const float* embed    = (const float*)d_in[2];
  const float* W_ih     = (const float*)d_in[3];
  const float* W_hh     = (const float*)d_in[4];
  const float* b_ih     = (const float*)d_in[5];
  const float* b_hh     = (const float*)d_in[6];
  const float* W_v      = (const float*)d_in[7];
  const float* W_g      = (const float*)d_in[8];
  const float* w_h      = (const float*)d_in[9];
  const float* W_p_w    = (const float*)d_in[10];
  const float* W_p_b    = (const float*)d_in[11];
  const float* W_init_h = (const float*)d_in[12];
  const float* W_init_m = (const float*)d_in[13];
  float* out = (float*)d_out;

  // ---- ws layout (bytes) ----
  char* base = (char*)d_ws;
  float* sp    = (float*)(base + 0);             // 6272*512*4      = 12,845,056
  float* WgT   = (float*)(base + 12845056);      // 512*2048*4      =  4,194,304
  float* h     = (float*)(base + 17039360);      // 128*2048*4      =  1,048,576
  float* m     = (float*)(base + 18087936);      //                  1,048,576
  float* a     = (float*)(base + 19136512);      //                  1,048,576
  short* h_hi  = (short*)(base + 20185088);      // 128*2048*2      =    524,288
  short* h_lo  = (short*)(base + 20709376);
  short* a_hi  = (short*)(base + 21233664);
  short* a_lo  = (short*)(base + 21757952);
  short* xh_hi = (short*)(base + 22282240);      // 128*4608*2      =  1,179,648
  short* xh_lo = (short*)(base + 23461888);
  int*   tok   = (int*)  (base + 24641536);      //                        512
  float* arena = (float*)(base + 24642048);      // 33,554,432 (max: gates S=8)
  const size_t needed = 58196480;
  if (ws_size < needed) return;

  float* tokout = out + (long)B_ * T_ * V_;

  init_tok_k<<<1, 128, 0, stream>>>(tok);

  // ---- prep: sp = spatial @ W_v  (transpose W_v into arena, then MFMA) ----
  transpose_f32<<<dim3(KA_/64, D_/64), 256, 0, stream>>>(W_v, D_, KA_, arena);
  gemm_mfma<true><<<dim3(4, 1, 49), 256, 0, stream>>>(
      spatial, nullptr, D_, arena, D_, nullptr, 0, 1<<30,
      sp, B_*L_, KA_, KA_, D_);
  // ---- prep: WgT (persistent) ----
  transpose_f32<<<dim3(KA_/64, H_/64), 256, 0, stream>>>(W_g, H_, KA_, WgT);
  // ---- prep: h0 = tanh(global_ @ W_init_h) ----
  {
    float* WT  = arena;                       // 2048*2048*4 = 16,777,216
    float* prt = arena + 4194304;             // partials S=4: 4*128*2048*4 = 4,194,304
    transpose_f32<<<dim3(H_/64, D_/64), 256, 0, stream>>>(W_init_h, D_, H_, WT);
    gemm_mfma<true><<<dim3(16, 4, 1), 256, 0, stream>>>(
        global_, nullptr, D_, WT, D_, nullptr, 0, 1<<30,
        prt, B_, H_, H_, 512);
    reduce_tanh_k<<<(B_*H_)/256, 256, 0, stream>>>(prt, h, h_hi, h_lo);
    transpose_f32<<<dim3(H_/64, D_/64), 256, 0, stream>>>(W_init_m, D_, H_, WT);
    gemm_mfma<true><<<dim3(16, 4, 1), 256, 0, stream>>>(
        global_, nullptr, D_, WT, D_, nullptr, 0, 1<<30,
        prt, B_, H_, H_, 512);
    reduce_tanh_k<<<(B_*H_)/256, 256, 0, stream>>>(prt, m, nullptr, nullptr);
  }

  // ---- decode loop ----
  for (int t = 0; t < T_; ++t) {
    gather_xh_k<<<B_, 256, 0, stream>>>(embed, global_, h, h_hi, h_lo, tok, xh_hi, xh_lo);
    // gates partials: S=8, k_len=576, dual weights split at k=2560
    gemm_mfma<false><<<dim3(64, 8, 1), 256, 0, stream>>>(
        xh_hi, xh_lo, KT_, W_ih, ED_, W_hh, H_, ED_,
        arena, B_, H4_, H4_, 576);
    lstm_reduce_k<<<(B_*H_)/256, 256, 0, stream>>>(arena, b_ih, b_hh, h, m, h_hi, h_lo);
    // hg partials: S=16, k_len=128
    gemm_mfma<false><<<dim3(4, 16, 1), 256, 0, stream>>>(
        h_hi, h_lo, H_, WgT, H_, nullptr, 0, 1<<30,
        arena, B_, KA_, KA_, 128);
    attn_k<<<dim3(B_, 2), 256, 0, stream>>>(sp, arena, w_h, spatial, h, a, a_hi, a_lo);
    // logits partials: S=4, k_len=512, padded N=10112
    gemm_mfma<false><<<dim3(79, 4, 1), 256, 0, stream>>>(
        a_hi, a_lo, H_, W_p_w, H_, nullptr, 0, 1<<30,
        arena, B_, VP_, V_, 512);
    logits_argmax_k<<<B_, 256, 0, stream>>>(arena, W_p_b, out + (long)t * V_, tok, tokout + t);
  }
}

// Round 3
// 6414.663 us; speedup vs baseline: 5.0854x; 1.0443x over previous
//
#include <hip/hip_runtime.h>
#include <math.h>

// Model_13348758356240 — R3: pre-split bf16 hi/lo weight planes (no per-step VALU split),
// split-K everywhere, fused reduce epilogues. Fallback to R2 path if ws too small.

typedef __attribute__((ext_vector_type(8))) short bf16x8;
typedef __attribute__((ext_vector_type(4))) float f32x4;

#define B_ 128
#define L_ 49
#define D_ 2048
#define H_ 2048
#define E_ 512
#define KA_ 512
#define V_ 10000
#define T_ 20
#define ED_ 2560
#define KT_ 4608
#define H4_ 8192
#define VP_ 10112

__device__ __forceinline__ void split1(float x, short* hi, short* lo){
  unsigned u = __float_as_uint(x);
  *hi = (short)(u >> 16);
  float r = x - __uint_as_float(u & 0xffff0000u);
  *lo = (short)(__float_as_uint(r) >> 16);
}
__device__ __forceinline__ void split8(float4 a, float4 b, bf16x8& h, bf16x8& l){
  float xs[8] = {a.x,a.y,a.z,a.w,b.x,b.y,b.z,b.w};
#pragma unroll
  for (int i=0;i<8;++i){
    unsigned u = __float_as_uint(xs[i]);
    h[i] = (short)(u>>16);
    float r = xs[i] - __uint_as_float(u & 0xffff0000u);
    l[i] = (short)(__float_as_uint(r)>>16);
  }
}

// ============ GEMM with pre-split W planes: Cp = A @ W^T (K-slice) ============
// W planes: bf16 [Np][ldw] (pad rows zeroed). A: pre-split shorts or fp32 (AF32).
// Wave: 128M x 32N. Block: 4 waves (128N). Grid (nb, S, mb).
template<bool AF32>
__global__ __launch_bounds__(256)
void gemm_ws(const void* Ahv, const void* Alv, int lda,
             const short* __restrict__ Wh, const short* __restrict__ Wl, int ldw,
             float* __restrict__ Cp, int Mtot, int Np, int k_len)
{
  const int tid = threadIdx.x;
  const int wid = tid >> 6, lane = tid & 63;
  const int lr = lane & 15, lg = lane >> 4;
  const int m0 = blockIdx.z * 128;
  const int nw = blockIdx.x * 128 + wid * 32;
  const int kb = blockIdx.y * k_len;
  const long rA = (long)(nw + lr) * ldw;
  const long rB = (long)(nw + 16 + lr) * ldw;

  f32x4 acc[8][2];
#pragma unroll
  for (int i=0;i<8;++i)
#pragma unroll
    for (int r=0;r<4;++r){ acc[i][0][r]=0.f; acc[i][1][r]=0.f; }

  for (int kk = 0; kk < k_len; kk += 32) {
    const int ko = kb + kk + 8*lg;
    const bf16x8 whA = *(const bf16x8*)(Wh + rA + ko);
    const bf16x8 wlA = *(const bf16x8*)(Wl + rA + ko);
    const bf16x8 whB = *(const bf16x8*)(Wh + rB + ko);
    const bf16x8 wlB = *(const bf16x8*)(Wl + rB + ko);

    bf16x8 ah[8], al[8];
    if constexpr (AF32) {
      const float* Af = (const float*)Ahv;
#pragma unroll
      for (int mt=0; mt<8; ++mt){
        const float* ap = Af + (long)(m0 + mt*16 + lr)*lda + ko;
        split8(*(const float4*)ap, *(const float4*)(ap+4), ah[mt], al[mt]);
      }
    } else {
      const short* Ah = (const short*)Ahv;
      const short* Al = (const short*)Alv;
#pragma unroll
      for (int mt=0; mt<8; ++mt){
        const long off = (long)(m0 + mt*16 + lr)*lda + ko;
        ah[mt] = *(const bf16x8*)(Ah + off);
        al[mt] = *(const bf16x8*)(Al + off);
      }
    }
#pragma unroll
    for (int mt=0; mt<8; ++mt){
      acc[mt][0] = __builtin_amdgcn_mfma_f32_16x16x32_bf16(ah[mt], whA, acc[mt][0], 0,0,0);
      acc[mt][1] = __builtin_amdgcn_mfma_f32_16x16x32_bf16(ah[mt], whB, acc[mt][1], 0,0,0);
      acc[mt][0] = __builtin_amdgcn_mfma_f32_16x16x32_bf16(ah[mt], wlA, acc[mt][0], 0,0,0);
      acc[mt][1] = __builtin_amdgcn_mfma_f32_16x16x32_bf16(ah[mt], wlB, acc[mt][1], 0,0,0);
      acc[mt][0] = __builtin_amdgcn_mfma_f32_16x16x32_bf16(al[mt], whA, acc[mt][0], 0,0,0);
      acc[mt][1] = __builtin_amdgcn_mfma_f32_16x16x32_bf16(al[mt], whB, acc[mt][1], 0,0,0);
    }
  }

  const long srow = (long)blockIdx.y * Mtot + m0;
#pragma unroll
  for (int mt=0; mt<8; ++mt)
#pragma unroll
    for (int nt=0; nt<2; ++nt){
      const int col = nw + nt*16 + lr;
#pragma unroll
      for (int r=0; r<4; ++r)
        Cp[(srow + mt*16 + 4*lg + r)*Np + col] = acc[mt][nt][r];
    }
}

// ============ R2 fallback GEMM: fp32 W, on-the-fly split, dual-W splice ============
template<bool AF32>
__global__ __launch_bounds__(256)
void gemm_mfma(const void* Ahv, const void* Alv, int lda,
               const float* __restrict__ W1, int ldw1,
               const float* __restrict__ W2, int ldw2, int ksplit,
               float* __restrict__ Cp, int Mtot, int Np, int Nvalid, int k_len)
{
  const int tid = threadIdx.x;
  const int wid = tid >> 6, lane = tid & 63;
  const int lr = lane & 15, lg = lane >> 4;
  const int m0 = blockIdx.z * 128;
  const int nw = blockIdx.x * 128 + wid * 32;
  const int kb = blockIdx.y * k_len;

  int rowA = nw + lr;       if (rowA >= Nvalid) rowA = Nvalid - 1;
  int rowB = nw + 16 + lr;  if (rowB >= Nvalid) rowB = Nvalid - 1;

  f32x4 acc[8][2];
#pragma unroll
  for (int i=0;i<8;++i)
#pragma unroll
    for (int r=0;r<4;++r){ acc[i][0][r]=0.f; acc[i][1][r]=0.f; }

  for (int kk = 0; kk < k_len; kk += 32) {
    const int kg = kb + kk;
    const float *pA, *pB;
    if (W2 && kg >= ksplit) {
      pA = W2 + (long)rowA*ldw2 + (kg - ksplit) + 8*lg;
      pB = W2 + (long)rowB*ldw2 + (kg - ksplit) + 8*lg;
    } else {
      pA = W1 + (long)rowA*ldw1 + kg + 8*lg;
      pB = W1 + (long)rowB*ldw1 + kg + 8*lg;
    }
    bf16x8 whA, wlA, whB, wlB;
    split8(*(const float4*)pA, *(const float4*)(pA+4), whA, wlA);
    split8(*(const float4*)pB, *(const float4*)(pB+4), whB, wlB);

    bf16x8 ah[8], al[8];
    if constexpr (AF32) {
      const float* Af = (const float*)Ahv;
#pragma unroll
      for (int mt=0; mt<8; ++mt){
        const float* ap = Af + (long)(m0 + mt*16 + lr)*lda + kg + 8*lg;
        split8(*(const float4*)ap, *(const float4*)(ap+4), ah[mt], al[mt]);
      }
    } else {
      const short* Ah = (const short*)Ahv;
      const short* Al = (const short*)Alv;
#pragma unroll
      for (int mt=0; mt<8; ++mt){
        const long off = (long)(m0 + mt*16 + lr)*lda + kg + 8*lg;
        ah[mt] = *(const bf16x8*)(Ah + off);
        al[mt] = *(const bf16x8*)(Al + off);
      }
    }
#pragma unroll
    for (int mt=0; mt<8; ++mt){
      acc[mt][0] = __builtin_amdgcn_mfma_f32_16x16x32_bf16(ah[mt], whA, acc[mt][0], 0,0,0);
      acc[mt][1] = __builtin_amdgcn_mfma_f32_16x16x32_bf16(ah[mt], whB, acc[mt][1], 0,0,0);
      acc[mt][0] = __builtin_amdgcn_mfma_f32_16x16x32_bf16(ah[mt], wlA, acc[mt][0], 0,0,0);
      acc[mt][1] = __builtin_amdgcn_mfma_f32_16x16x32_bf16(ah[mt], wlB, acc[mt][1], 0,0,0);
      acc[mt][0] = __builtin_amdgcn_mfma_f32_16x16x32_bf16(al[mt], whA, acc[mt][0], 0,0,0);
      acc[mt][1] = __builtin_amdgcn_mfma_f32_16x16x32_bf16(al[mt], whB, acc[mt][1], 0,0,0);
    }
  }

  const long srow = (long)blockIdx.y * Mtot + m0;
#pragma unroll
  for (int mt=0; mt<8; ++mt)
#pragma unroll
    for (int nt=0; nt<2; ++nt){
      const int col = nw + nt*16 + lr;
#pragma unroll
      for (int r=0; r<4; ++r)
        Cp[(srow + mt*16 + 4*lg + r)*Np + col] = acc[mt][nt][r];
    }
}

// ============ prep kernels ============
// fp32 [n<Nv][Kin] -> bf16 planes row n at [ldo], k offset ko; rows >= Nv zeroed.
__global__ __launch_bounds__(256)
void split_nt_k(const float* __restrict__ W, int Nv, int Kin,
                short* __restrict__ Wh, short* __restrict__ Wl, int ldo, int ko)
{
  const int n = blockIdx.y;
  const int k = blockIdx.x * 1024 + threadIdx.x * 4;
  if (k >= Kin) return;
  short4 hv, lv;
  if (n < Nv) {
    const float4 v = *(const float4*)&W[(long)n*Kin + k];
    split1(v.x, &hv.x, &lv.x); split1(v.y, &hv.y, &lv.y);
    split1(v.z, &hv.z, &lv.z); split1(v.w, &hv.w, &lv.w);
  } else {
    hv.x=hv.y=hv.z=hv.w=0; lv.x=lv.y=lv.z=lv.w=0;
  }
  *(short4*)&Wh[(long)n*ldo + ko + k] = hv;
  *(short4*)&Wl[(long)n*ldo + ko + k] = lv;
}

// fp32 [K][N] -> transposed bf16 planes [N][K]
__global__ __launch_bounds__(256)
void split_t_k(const float* __restrict__ in, int K, int N,
               short* __restrict__ Oh, short* __restrict__ Ol)
{
  __shared__ float t[64][65];
  const int tid = threadIdx.x;
  const int c0 = blockIdx.x * 64, r0 = blockIdx.y * 64;
  const int lx = tid & 63, ly = tid >> 6;
#pragma unroll
  for (int i = 0; i < 16; ++i)
    t[ly + 4*i][lx] = in[(long)(r0 + ly + 4*i) * N + c0 + lx];
  __syncthreads();
#pragma unroll
  for (int i = 0; i < 16; ++i) {
    short hh, ll;
    split1(t[lx][ly + 4*i], &hh, &ll);
    const long o = (long)(c0 + ly + 4*i) * K + r0 + lx;
    Oh[o] = hh; Ol[o] = ll;
  }
}

// fp32 tiled transpose (fallback path)
__global__ __launch_bounds__(256)
void transpose_f32(const float* __restrict__ in, int R, int C, float* __restrict__ out)
{
  __shared__ float t[64][65];
  const int tid = threadIdx.x;
  const int c0 = blockIdx.x * 64, r0 = blockIdx.y * 64;
  const int lx = tid & 63, ly = tid >> 6;
#pragma unroll
  for (int i = 0; i < 16; ++i)
    t[ly + 4*i][lx] = in[(long)(r0 + ly + 4*i) * C + c0 + lx];
  __syncthreads();
#pragma unroll
  for (int i = 0; i < 16; ++i)
    out[(long)(c0 + ly + 4*i) * R + r0 + lx] = t[lx][ly + 4*i];
}

__global__ void reduce_sp_k(const float4* __restrict__ p, float4* __restrict__ sp)
{
  const long i = (long)blockIdx.x * 256 + threadIdx.x;   // 802,816 float4s
  const long s = 802816;
  float4 a = p[i], b = p[i+s], c = p[i+2*s], d = p[i+3*s];
  float4 r;
  r.x = (a.x+b.x)+(c.x+d.x); r.y = (a.y+b.y)+(c.y+d.y);
  r.z = (a.z+b.z)+(c.z+d.z); r.w = (a.w+b.w)+(c.w+d.w);
  sp[i] = r;
}

// ============ step kernels ============
__global__ void init_tok_k(int* tok) {
  if (threadIdx.x < B_) tok[threadIdx.x] = 1; // START_IDX
}

__global__ __launch_bounds__(256)
void reduce_tanh_k(const float* __restrict__ gp, float* __restrict__ out,
                   short* __restrict__ ohi, short* __restrict__ olo)
{
  const int idx = blockIdx.x * 256 + threadIdx.x;
  float s = 0.f;
#pragma unroll
  for (int sl = 0; sl < 4; ++sl) s += gp[(long)sl * (B_*H_) + idx];
  s = tanhf(s);
  out[idx] = s;
  if (ohi) split1(s, &ohi[idx], &olo[idx]);
}

__global__ void gather_xh_k(const float* __restrict__ embed, const float* __restrict__ global_,
                            const short* __restrict__ h_hi, const short* __restrict__ h_lo,
                            const int* __restrict__ tok,
                            short* __restrict__ xh_hi, short* __restrict__ xh_lo)
{
  const int b = blockIdx.x, tid = threadIdx.x;
  const int tk = tok[b];
  short* rh = xh_hi + (long)b * KT_;
  short* rl = xh_lo + (long)b * KT_;
  const float* e = embed + (long)tk * E_;
  for (int i = tid; i < E_; i += 256) split1(e[i], &rh[i], &rl[i]);
  for (int i = tid; i < D_; i += 256) split1(global_[(long)b * D_ + i], &rh[E_ + i], &rl[E_ + i]);
  for (int i = tid; i < H_; i += 256) { rh[ED_ + i] = h_hi[(long)b * H_ + i]; rl[ED_ + i] = h_lo[(long)b * H_ + i]; }
}

__global__ __launch_bounds__(256)
void lstm_reduce_k(const float* __restrict__ gp, const float* __restrict__ b_ih,
                   const float* __restrict__ b_hh, float* __restrict__ h, float* __restrict__ m,
                   short* __restrict__ h_hi, short* __restrict__ h_lo)
{
  const int idx = blockIdx.x * 256 + threadIdx.x;
  const int b = idx >> 11, n = idx & (H_ - 1);
  float g[4];
#pragma unroll
  for (int j = 0; j < 4; ++j) {
    float s = b_ih[j*H_ + n] + b_hh[j*H_ + n];
#pragma unroll
    for (int sl = 0; sl < 8; ++sl) s += gp[((long)sl * B_ + b) * H4_ + j*H_ + n];
    g[j] = s;
  }
  const float si = 1.f / (1.f + expf(-g[0]));
  const float sf = 1.f / (1.f + expf(-g[1]));
  const float gg = tanhf(g[2]);
  const float so = 1.f / (1.f + expf(-g[3]));
  const float mn = sf * m[idx] + si * gg;
  const float hn = so * tanhf(mn);
  m[idx] = mn; h[idx] = hn;
  split1(hn, &h_hi[idx], &h_lo[idx]);
}

__global__ __launch_bounds__(256)
void attn_k(const float* __restrict__ sp_proj, const float* __restrict__ hgp,
            const float* __restrict__ w_h, const float* __restrict__ spatial,
            const float* __restrict__ h, float* __restrict__ a,
            short* __restrict__ a_hi, short* __restrict__ a_lo)
{
  const int b = blockIdx.x, half = blockIdx.y, tid = threadIdx.x;
  const int lane = tid & 63, wv = tid >> 6;
  __shared__ float hgs[KA_];
  __shared__ float whs[KA_];
  __shared__ float zs[L_];
  __shared__ float alph[L_];
  for (int i = tid; i < KA_; i += 256) {
    float s = 0.f;
#pragma unroll
    for (int sl = 0; sl < 16; ++sl) s += hgp[((long)sl * B_ + b) * KA_ + i];
    hgs[i] = s; whs[i] = w_h[i];
  }
  __syncthreads();
  for (int l = wv; l < L_; l += 4) {
    const float* sp = sp_proj + ((long)b * L_ + l) * KA_;
    float s = 0.f;
    for (int k = lane; k < KA_; k += 64) s += whs[k] * tanhf(sp[k] + hgs[k]);
#pragma unroll
    for (int off = 32; off > 0; off >>= 1) s += __shfl_down(s, off);
    if (lane == 0) zs[l] = s;
  }
  __syncthreads();
  if (wv == 0) {
    float v = (lane < L_) ? zs[lane] : -INFINITY;
    float mx = v;
#pragma unroll
    for (int off = 32; off > 0; off >>= 1) mx = fmaxf(mx, __shfl_xor(mx, off));
    float e = (lane < L_) ? expf(v - mx) : 0.f;
    float sum = e;
#pragma unroll
    for (int off = 32; off > 0; off >>= 1) sum += __shfl_xor(sum, off);
    if (lane < L_) alph[lane] = e / sum;
  }
  __syncthreads();
  // c + h: exactly one float4 per thread (half*1024 floats = 256 float4)
  const int d4 = half * 256 + tid;
  const float4* h4 = (const float4*)h;
  const float4* sp4 = (const float4*)spatial;
  float4 acc = h4[(long)b * 512 + d4];
#pragma unroll 7
  for (int l = 0; l < L_; ++l) {
    const float w = alph[l];
    const float4 v = sp4[((long)b * L_ + l) * 512 + d4];
    acc.x = fmaf(w, v.x, acc.x); acc.y = fmaf(w, v.y, acc.y);
    acc.z = fmaf(w, v.z, acc.z); acc.w = fmaf(w, v.w, acc.w);
  }
  ((float4*)a)[(long)b * 512 + d4] = acc;
  short4 hv, lv;
  split1(acc.x, &hv.x, &lv.x); split1(acc.y, &hv.y, &lv.y);
  split1(acc.z, &hv.z, &lv.z); split1(acc.w, &hv.w, &lv.w);
  *(short4*)&a_hi[(long)b * D_ + d4*4] = hv;
  *(short4*)&a_lo[(long)b * D_ + d4*4] = lv;
}

__global__ __launch_bounds__(256)
void logits_argmax_k(const float* __restrict__ lp, const float* __restrict__ bias,
                     float* __restrict__ outL, int* __restrict__ tok,
                     float* __restrict__ tokout)
{
  const int b = blockIdx.x, tid = threadIdx.x;
  float bv = -INFINITY; int bi = 0x7fffffff;
  for (int j = tid; j < V_; j += 256) {
    float v = bias[j];
#pragma unroll
    for (int sl = 0; sl < 4; ++sl) v += lp[((long)sl * B_ + b) * VP_ + j];
    outL[(long)b * (T_*V_) + j] = v;
    if (v > bv) { bv = v; bi = j; }
  }
  __shared__ float sv[256];
  __shared__ int   si[256];
  sv[tid] = bv; si[tid] = bi;
  __syncthreads();
  for (int s = 128; s > 0; s >>= 1) {
    if (tid < s) {
      const float ov = sv[tid + s]; const int oi = si[tid + s];
      if (ov > sv[tid] || (ov == sv[tid] && oi < si[tid])) { sv[tid] = ov; si[tid] = oi; }
    }
    __syncthreads();
  }
  if (tid == 0) { tok[b] = si[0]; tokout[(long)b * T_] = (float)si[0]; }
}

// ============ host ============
extern "C" void kernel_launch(void* const* d_in, const int* in_sizes, int n_in,
                              void* d_out, int out_size, void* d_ws, size_t ws_size,
                              hipStream_t stream)
{
  const float* spatial  = (const float*)d_in[0];
  const float* global_  = (const float*)d_in[1];
  const float* embed    = (const float*)d_in[2];
  const float* W_ih     = (const float*)d_in[3];
  const float* W_hh     = (const float*)d_in[4];
  const float* b_ih     = (const float*)d_in[5];
  const float* b_hh     = (const float*)d_in[6];
  const float* W_v      = (const float*)d_in[7];
  const float* W_g      = (const float*)d_in[8];
  const float* w_h      = (const float*)d_in[9];
  const float* W_p_w    = (const float*)d_in[10];
  const float* W_p_b    = (const float*)d_in[11];
  const float* W_init_h = (const float*)d_in[12];
  const float* W_init_m = (const float*)d_in[13];
  float* out = (float*)d_out;

  // ---- ws layout (byte offsets) ----
  char* base = (char*)d_ws;
  float* sp    = (float*)(base + 0);            // 12,845,056
  float* WvTf  = (float*)(base + 12845056);     //  4,194,304 (fallback)
  float* WgTf  = (float*)(base + 17039360);     //  4,194,304 (fallback)
  float* h     = (float*)(base + 21233664);     //  1,048,576
  float* m     = (float*)(base + 22282240);     //  1,048,576
  float* a     = (float*)(base + 23330816);     //  1,048,576
  short* h_hi  = (short*)(base + 24379392);     //    524,288
  short* h_lo  = (short*)(base + 24903680);
  short* a_hi  = (short*)(base + 25427968);
  short* a_lo  = (short*)(base + 25952256);
  short* xh_hi = (short*)(base + 26476544);     //  1,179,648
  short* xh_lo = (short*)(base + 27656192);
  int*   tok   = (int*)  (base + 28835840);     //        512
  float* arena = (float*)(base + 28836352);     // 33,554,432
  // pre-split weight planes
  short* Wcat_hi = (short*)(base + 62390784);   // 75,497,472  (8192 x 4608)
  short* Wcat_lo = (short*)(base + 137888256);  // 75,497,472
  short* Wp_hi   = (short*)(base + 213385728);  // 41,418,752  (10112 x 2048)
  short* Wp_lo   = (short*)(base + 254804480);  // 41,418,752
  short* WvT_hi  = (short*)(base + 296223232);  //  2,097,152  (512 x 2048)
  short* WvT_lo  = (short*)(base + 298320384);
  short* WgT_hi  = (short*)(base + 300417536);
  short* WgT_lo  = (short*)(base + 302514688);
  const size_t NEED_PRE = 304611840;
  const size_t NEED_FB  = 62390784;
  if (ws_size < NEED_FB) return;
  const bool pre = (ws_size >= NEED_PRE);

  float* tokout = out + (long)B_ * T_ * V_;

  init_tok_k<<<1, 128, 0, stream>>>(tok);

  if (pre) {
    // sp = spatial @ W_v (split-K S=4, partials staged in soon-to-be Wcat region)
    split_t_k<<<dim3(KA_/64, D_/64), 256, 0, stream>>>(W_v, D_, KA_, WvT_hi, WvT_lo);
    float* spp = (float*)Wcat_hi;  // 51.4 MB < 75.5 MB; overwritten after reduce
    gemm_ws<true><<<dim3(4, 4, 49), 256, 0, stream>>>(
        spatial, nullptr, D_, WvT_hi, WvT_lo, D_, spp, B_*L_, KA_, 512);
    reduce_sp_k<<<3136, 256, 0, stream>>>((const float4*)spp, (float4*)sp);
    // weight planes
    split_t_k<<<dim3(KA_/64, H_/64), 256, 0, stream>>>(W_g, H_, KA_, WgT_hi, WgT_lo);
    split_nt_k<<<dim3(3, H4_), 256, 0, stream>>>(W_ih, H4_, ED_, Wcat_hi, Wcat_lo, KT_, 0);
    split_nt_k<<<dim3(2, H4_), 256, 0, stream>>>(W_hh, H4_, H_,  Wcat_hi, Wcat_lo, KT_, ED_);
    split_nt_k<<<dim3(2, VP_), 256, 0, stream>>>(W_p_w, V_, H_,  Wp_hi,   Wp_lo,   H_, 0);
    // h0/m0 init (planes + partials in arena)
    short* WTh = (short*)arena;                       // 8,388,608 B
    short* WTl = (short*)((char*)arena + 8388608);    // 8,388,608 B
    float* prt = (float*)((char*)arena + 16777216);   // 4,194,304 B
    split_t_k<<<dim3(H_/64, D_/64), 256, 0, stream>>>(W_init_h, D_, H_, WTh, WTl);
    gemm_ws<true><<<dim3(16, 4, 1), 256, 0, stream>>>(
        global_, nullptr, D_, WTh, WTl, D_, prt, B_, H_, 512);
    reduce_tanh_k<<<(B_*H_)/256, 256, 0, stream>>>(prt, h, h_hi, h_lo);
    split_t_k<<<dim3(H_/64, D_/64), 256, 0, stream>>>(W_init_m, D_, H_, WTh, WTl);
    gemm_ws<true><<<dim3(16, 4, 1), 256, 0, stream>>>(
        global_, nullptr, D_, WTh, WTl, D_, prt, B_, H_, 512);
    reduce_tanh_k<<<(B_*H_)/256, 256, 0, stream>>>(prt, m, nullptr, nullptr);

    for (int t = 0; t < T_; ++t) {
      gather_xh_k<<<B_, 256, 0, stream>>>(embed, global_, h_hi, h_lo, tok, xh_hi, xh_lo);
      gemm_ws<false><<<dim3(64, 8, 1), 256, 0, stream>>>(
          xh_hi, xh_lo, KT_, Wcat_hi, Wcat_lo, KT_, arena, B_, H4_, 576);
      lstm_reduce_k<<<(B_*H_)/256, 256, 0, stream>>>(arena, b_ih, b_hh, h, m, h_hi, h_lo);
      gemm_ws<false><<<dim3(4, 16, 1), 256, 0, stream>>>(
          h_hi, h_lo, H_, WgT_hi, WgT_lo, H_, arena, B_, KA_, 128);
      attn_k<<<dim3(B_, 2), 256, 0, stream>>>(sp, arena, w_h, spatial, h, a, a_hi, a_lo);
      gemm_ws<false><<<dim3(79, 4, 1), 256, 0, stream>>>(
          a_hi, a_lo, H_, Wp_hi, Wp_lo, H_, arena, B_, VP_, 512);
      logits_argmax_k<<<B_, 256, 0, stream>>>(arena, W_p_b, out + (long)t * V_, tok, tokout + t);
    }
  } else {
    // -------- R2 fallback: fp32 weights, on-the-fly split --------
    transpose_f32<<<dim3(KA_/64, D_/64), 256, 0, stream>>>(W_v, D_, KA_, WvTf);
    gemm_mfma<true><<<dim3(4, 1, 49), 256, 0, stream>>>(
        spatial, nullptr, D_, WvTf, D_, nullptr, 0, 1<<30, sp, B_*L_, KA_, KA_, D_);
    transpose_f32<<<dim3(KA_/64, H_/64), 256, 0, stream>>>(W_g, H_, KA_, WgTf);
    {
      float* WT  = arena;
      float* prt = (float*)((char*)arena + 16777216);
      transpose_f32<<<dim3(H_/64, D_/64), 256, 0, stream>>>(W_init_h, D_, H_, WT);
      gemm_mfma<true><<<dim3(16, 4, 1), 256, 0, stream>>>(
          global_, nullptr, D_, WT, D_, nullptr, 0, 1<<30, prt, B_, H_, H_, 512);
      reduce_tanh_k<<<(B_*H_)/256, 256, 0, stream>>>(prt, h, h_hi, h_lo);
      transpose_f32<<<dim3(H_/64, D_/64), 256, 0, stream>>>(W_init_m, D_, H_, WT);
      gemm_mfma<true><<<dim3(16, 4, 1), 256, 0, stream>>>(
          global_, nullptr, D_, WT, D_, nullptr, 0, 1<<30, prt, B_, H_, H_, 512);
      reduce_tanh_k<<<(B_*H_)/256, 256, 0, stream>>>(prt, m, nullptr, nullptr);
    }
    for (int t = 0; t < T_; ++t) {
      gather_xh_k<<<B_, 256, 0, stream>>>(embed, global_, h_hi, h_lo, tok, xh_hi, xh_lo);
      gemm_mfma<false><<<dim3(64, 8, 1), 256, 0, stream>>>(
          xh_hi, xh_lo, KT_, W_ih, ED_, W_hh, H_, ED_, arena, B_, H4_, H4_, 576);
      lstm_reduce_k<<<(B_*H_)/256, 256, 0, stream>>>(arena, b_ih, b_hh, h, m, h_hi, h_lo);
      gemm_mfma<false><<<dim3(4, 16, 1), 256, 0, stream>>>(
          h_hi, h_lo, H_, WgTf, H_, nullptr, 0, 1<<30, arena, B_, KA_, KA_, 128);
      attn_k<<<dim3(B_, 2), 256, 0, stream>>>(sp, arena, w_h, spatial, h, a, a_hi, a_lo);
      gemm_mfma<false><<<dim3(79, 4, 1), 256, 0, stream>>>(
          a_hi, a_lo, H_, W_p_w, H_, nullptr, 0, 1<<30, arena, B_, VP_, V_, 512);
      logits_argmax_k<<<B_, 256, 0, stream>>>(arena, W_p_b, out + (long)t * V_, tok, tokout + t);
    }
  }
}

// Round 4
// 5899.842 us; speedup vs baseline: 5.5291x; 1.0873x over previous
//
#include <hip/hip_runtime.h>
#include <math.h>

// Model_13348758356240 — R4: depth-2 W-prefetch MFMA GEMM, all-plane A inputs
// (no VALU split in hot loops), bigger split-K grids, fused argmax+gather.

typedef __attribute__((ext_vector_type(8))) short bf16x8;
typedef __attribute__((ext_vector_type(4))) float f32x4;

#define B_ 128
#define L_ 49
#define D_ 2048
#define H_ 2048
#define E_ 512
#define KA_ 512
#define V_ 10000
#define T_ 20
#define ED_ 2560
#define KT_ 4608
#define H4_ 8192
#define VP_ 10112

__device__ __forceinline__ void split1(float x, short* hi, short* lo){
  unsigned u = __float_as_uint(x);
  *hi = (short)(u >> 16);
  float r = x - __uint_as_float(u & 0xffff0000u);
  *lo = (short)(__float_as_uint(r) >> 16);
}
__device__ __forceinline__ void split8(float4 a, float4 b, bf16x8& h, bf16x8& l){
  float xs[8] = {a.x,a.y,a.z,a.w,b.x,b.y,b.z,b.w};
#pragma unroll
  for (int i=0;i<8;++i){
    unsigned u = __float_as_uint(xs[i]);
    h[i] = (short)(u>>16);
    float r = xs[i] - __uint_as_float(u & 0xffff0000u);
    l[i] = (short)(__float_as_uint(r)>>16);
  }
}

#define MFMA16(d,a,b,c) d = __builtin_amdgcn_mfma_f32_16x16x32_bf16(a,b,c,0,0,0)

// ============ R4 GEMM: Cp = A @ W^T (K-slice), depth-2 W prefetch ============
// A planes: bf16 [Mtot][lda]; W planes: bf16 [Np][ldw] (pad rows zeroed).
// Wave: 128M x 32N. Block: 4 waves (128N). Grid (nb, S, mb). k_len % 64 == 0.
__global__ __launch_bounds__(256)
void gemm_ws(const short* __restrict__ Ah, const short* __restrict__ Al, int lda,
             const short* __restrict__ Wh, const short* __restrict__ Wl, int ldw,
             float* __restrict__ Cp, int Mtot, int Np, int k_len)
{
  const int tid = threadIdx.x;
  const int wid = tid >> 6, lane = tid & 63;
  const int lr = lane & 15, lg = lane >> 4;
  const int m0 = blockIdx.z * 128;
  const int nw = blockIdx.x * 128 + wid * 32;
  const int kb = blockIdx.y * k_len;
  const long rA = (long)(nw + lr) * ldw;
  const long rB = (long)(nw + 16 + lr) * ldw;
  const int kmax = ldw - 8;

  f32x4 acc[8][2];
#pragma unroll
  for (int i=0;i<8;++i)
#pragma unroll
    for (int r=0;r<4;++r){ acc[i][0][r]=0.f; acc[i][1][r]=0.f; }

  const int k0 = kb + 8*lg;
  bf16x8 w0hA = *(const bf16x8*)(Wh + rA + k0);
  bf16x8 w0lA = *(const bf16x8*)(Wl + rA + k0);
  bf16x8 w0hB = *(const bf16x8*)(Wh + rB + k0);
  bf16x8 w0lB = *(const bf16x8*)(Wl + rB + k0);
  const int k1 = k0 + 32;
  bf16x8 w1hA = *(const bf16x8*)(Wh + rA + k1);
  bf16x8 w1lA = *(const bf16x8*)(Wl + rA + k1);
  bf16x8 w1hB = *(const bf16x8*)(Wh + rB + k1);
  bf16x8 w1lB = *(const bf16x8*)(Wl + rB + k1);

  const long ab = (long)(m0 + lr) * lda + kb + 8*lg;

  for (int kk = 0; kk < k_len; kk += 64) {
    { // sub-step 0: consume w0, prefetch w0 <- k0+kk+64
      bf16x8 ah[8], al[8];
#pragma unroll
      for (int mt=0; mt<8; ++mt){
        const long o = ab + (long)mt*16*lda + kk;
        ah[mt] = *(const bf16x8*)(Ah + o);
        al[mt] = *(const bf16x8*)(Al + o);
      }
#pragma unroll
      for (int mt=0; mt<8; ++mt){
        MFMA16(acc[mt][0], ah[mt], w0hA, acc[mt][0]);
        MFMA16(acc[mt][1], ah[mt], w0hB, acc[mt][1]);
        MFMA16(acc[mt][0], ah[mt], w0lA, acc[mt][0]);
        MFMA16(acc[mt][1], ah[mt], w0lB, acc[mt][1]);
        MFMA16(acc[mt][0], al[mt], w0hA, acc[mt][0]);
        MFMA16(acc[mt][1], al[mt], w0hB, acc[mt][1]);
      }
      int kp = k0 + kk + 64; if (kp > kmax) kp = kmax;
      w0hA = *(const bf16x8*)(Wh + rA + kp);
      w0lA = *(const bf16x8*)(Wl + rA + kp);
      w0hB = *(const bf16x8*)(Wh + rB + kp);
      w0lB = *(const bf16x8*)(Wl + rB + kp);
    }
    { // sub-step 1: consume w1, prefetch w1 <- k1+kk+64
      bf16x8 ah[8], al[8];
#pragma unroll
      for (int mt=0; mt<8; ++mt){
        const long o = ab + (long)mt*16*lda + kk + 32;
        ah[mt] = *(const bf16x8*)(Ah + o);
        al[mt] = *(const bf16x8*)(Al + o);
      }
#pragma unroll
      for (int mt=0; mt<8; ++mt){
        MFMA16(acc[mt][0], ah[mt], w1hA, acc[mt][0]);
        MFMA16(acc[mt][1], ah[mt], w1hB, acc[mt][1]);
        MFMA16(acc[mt][0], ah[mt], w1lA, acc[mt][0]);
        MFMA16(acc[mt][1], ah[mt], w1lB, acc[mt][1]);
        MFMA16(acc[mt][0], al[mt], w1hA, acc[mt][0]);
        MFMA16(acc[mt][1], al[mt], w1hB, acc[mt][1]);
      }
      int kp = k1 + kk + 64; if (kp > kmax) kp = kmax;
      w1hA = *(const bf16x8*)(Wh + rA + kp);
      w1lA = *(const bf16x8*)(Wl + rA + kp);
      w1hB = *(const bf16x8*)(Wh + rB + kp);
      w1lB = *(const bf16x8*)(Wl + rB + kp);
    }
  }

  const long srow = (long)blockIdx.y * Mtot + m0;
#pragma unroll
  for (int mt=0; mt<8; ++mt)
#pragma unroll
    for (int nt=0; nt<2; ++nt){
      const int col = nw + nt*16 + lr;
#pragma unroll
      for (int r=0; r<4; ++r)
        Cp[(srow + mt*16 + 4*lg + r)*Np + col] = acc[mt][nt][r];
    }
}

// ============ R2/R3 fallback GEMM: fp32 W, on-the-fly split ============
template<bool AF32>
__global__ __launch_bounds__(256)
void gemm_mfma(const void* Ahv, const void* Alv, int lda,
               const float* __restrict__ W1, int ldw1,
               const float* __restrict__ W2, int ldw2, int ksplit,
               float* __restrict__ Cp, int Mtot, int Np, int Nvalid, int k_len)
{
  const int tid = threadIdx.x;
  const int wid = tid >> 6, lane = tid & 63;
  const int lr = lane & 15, lg = lane >> 4;
  const int m0 = blockIdx.z * 128;
  const int nw = blockIdx.x * 128 + wid * 32;
  const int kb = blockIdx.y * k_len;

  int rowA = nw + lr;       if (rowA >= Nvalid) rowA = Nvalid - 1;
  int rowB = nw + 16 + lr;  if (rowB >= Nvalid) rowB = Nvalid - 1;

  f32x4 acc[8][2];
#pragma unroll
  for (int i=0;i<8;++i)
#pragma unroll
    for (int r=0;r<4;++r){ acc[i][0][r]=0.f; acc[i][1][r]=0.f; }

  for (int kk = 0; kk < k_len; kk += 32) {
    const int kg = kb + kk;
    const float *pA, *pB;
    if (W2 && kg >= ksplit) {
      pA = W2 + (long)rowA*ldw2 + (kg - ksplit) + 8*lg;
      pB = W2 + (long)rowB*ldw2 + (kg - ksplit) + 8*lg;
    } else {
      pA = W1 + (long)rowA*ldw1 + kg + 8*lg;
      pB = W1 + (long)rowB*ldw1 + kg + 8*lg;
    }
    bf16x8 whA, wlA, whB, wlB;
    split8(*(const float4*)pA, *(const float4*)(pA+4), whA, wlA);
    split8(*(const float4*)pB, *(const float4*)(pB+4), whB, wlB);

    bf16x8 ah[8], al[8];
    if constexpr (AF32) {
      const float* Af = (const float*)Ahv;
#pragma unroll
      for (int mt=0; mt<8; ++mt){
        const float* ap = Af + (long)(m0 + mt*16 + lr)*lda + kg + 8*lg;
        split8(*(const float4*)ap, *(const float4*)(ap+4), ah[mt], al[mt]);
      }
    } else {
      const short* Ah = (const short*)Ahv;
      const short* Al = (const short*)Alv;
#pragma unroll
      for (int mt=0; mt<8; ++mt){
        const long off = (long)(m0 + mt*16 + lr)*lda + kg + 8*lg;
        ah[mt] = *(const bf16x8*)(Ah + off);
        al[mt] = *(const bf16x8*)(Al + off);
      }
    }
#pragma unroll
    for (int mt=0; mt<8; ++mt){
      MFMA16(acc[mt][0], ah[mt], whA, acc[mt][0]);
      MFMA16(acc[mt][1], ah[mt], whB, acc[mt][1]);
      MFMA16(acc[mt][0], ah[mt], wlA, acc[mt][0]);
      MFMA16(acc[mt][1], ah[mt], wlB, acc[mt][1]);
      MFMA16(acc[mt][0], al[mt], whA, acc[mt][0]);
      MFMA16(acc[mt][1], al[mt], whB, acc[mt][1]);
    }
  }

  const long srow = (long)blockIdx.y * Mtot + m0;
#pragma unroll
  for (int mt=0; mt<8; ++mt)
#pragma unroll
    for (int nt=0; nt<2; ++nt){
      const int col = nw + nt*16 + lr;
#pragma unroll
      for (int r=0; r<4; ++r)
        Cp[(srow + mt*16 + 4*lg + r)*Np + col] = acc[mt][nt][r];
    }
}

// ============ prep kernels ============
__global__ __launch_bounds__(256)
void split_nt_k(const float* __restrict__ W, int Nv, int Kin,
                short* __restrict__ Wh, short* __restrict__ Wl, int ldo, int ko)
{
  const int n = blockIdx.y;
  const int k = blockIdx.x * 1024 + threadIdx.x * 4;
  if (k >= Kin) return;
  short4 hv, lv;
  if (n < Nv) {
    const float4 v = *(const float4*)&W[(long)n*Kin + k];
    split1(v.x, &hv.x, &lv.x); split1(v.y, &hv.y, &lv.y);
    split1(v.z, &hv.z, &lv.z); split1(v.w, &hv.w, &lv.w);
  } else {
    hv.x=hv.y=hv.z=hv.w=0; lv.x=lv.y=lv.z=lv.w=0;
  }
  *(short4*)&Wh[(long)n*ldo + ko + k] = hv;
  *(short4*)&Wl[(long)n*ldo + ko + k] = lv;
}

__global__ __launch_bounds__(256)
void split_t_k(const float* __restrict__ in, int K, int N,
               short* __restrict__ Oh, short* __restrict__ Ol)
{
  __shared__ float t[64][65];
  const int tid = threadIdx.x;
  const int c0 = blockIdx.x * 64, r0 = blockIdx.y * 64;
  const int lx = tid & 63, ly = tid >> 6;
#pragma unroll
  for (int i = 0; i < 16; ++i)
    t[ly + 4*i][lx] = in[(long)(r0 + ly + 4*i) * N + c0 + lx];
  __syncthreads();
#pragma unroll
  for (int i = 0; i < 16; ++i) {
    short hh, ll;
    split1(t[lx][ly + 4*i], &hh, &ll);
    const long o = (long)(c0 + ly + 4*i) * K + r0 + lx;
    Oh[o] = hh; Ol[o] = ll;
  }
}

// fp32 array -> bf16 hi/lo planes, same layout (n multiple of 4)
__global__ __launch_bounds__(256)
void split_plane_k(const float* __restrict__ in, long n,
                   short* __restrict__ oh, short* __restrict__ ol)
{
  const long i = ((long)blockIdx.x * 256 + threadIdx.x) * 4;
  if (i >= n) return;
  const float4 v = *(const float4*)&in[i];
  short4 hv, lv;
  split1(v.x, &hv.x, &lv.x); split1(v.y, &hv.y, &lv.y);
  split1(v.z, &hv.z, &lv.z); split1(v.w, &hv.w, &lv.w);
  *(short4*)&oh[i] = hv;
  *(short4*)&ol[i] = lv;
}

__global__ __launch_bounds__(256)
void transpose_f32(const float* __restrict__ in, int R, int C, float* __restrict__ out)
{
  __shared__ float t[64][65];
  const int tid = threadIdx.x;
  const int c0 = blockIdx.x * 64, r0 = blockIdx.y * 64;
  const int lx = tid & 63, ly = tid >> 6;
#pragma unroll
  for (int i = 0; i < 16; ++i)
    t[ly + 4*i][lx] = in[(long)(r0 + ly + 4*i) * C + c0 + lx];
  __syncthreads();
#pragma unroll
  for (int i = 0; i < 16; ++i)
    out[(long)(c0 + ly + 4*i) * R + r0 + lx] = t[lx][ly + 4*i];
}

__global__ void reduce_sp_k(const float4* __restrict__ p, float4* __restrict__ sp)
{
  const long i = (long)blockIdx.x * 256 + threadIdx.x;   // 802,816 float4s
  const long s = 802816;
  float4 a = p[i], b = p[i+s], c = p[i+2*s], d = p[i+3*s];
  float4 r;
  r.x = (a.x+b.x)+(c.x+d.x); r.y = (a.y+b.y)+(c.y+d.y);
  r.z = (a.z+b.z)+(c.z+d.z); r.w = (a.w+b.w)+(c.w+d.w);
  sp[i] = r;
}

// ============ step kernels ============
__global__ void init_tok_k(int* tok) {
  if (threadIdx.x < B_) tok[threadIdx.x] = 1; // START_IDX
}

__global__ __launch_bounds__(256)
void reduce_tanh_k(const float* __restrict__ gp, int S, float* __restrict__ out,
                   short* __restrict__ ohi, short* __restrict__ olo)
{
  const int idx = blockIdx.x * 256 + threadIdx.x;
  float s = 0.f;
  for (int sl = 0; sl < S; ++sl) s += gp[(long)sl * (B_*H_) + idx];
  s = tanhf(s);
  out[idx] = s;
  if (ohi) split1(s, &ohi[idx], &olo[idx]);
}

__global__ void gather_xh_k(const float* __restrict__ embed, const float* __restrict__ global_,
                            const short* __restrict__ h_hi, const short* __restrict__ h_lo,
                            const int* __restrict__ tok,
                            short* __restrict__ xh_hi, short* __restrict__ xh_lo)
{
  const int b = blockIdx.x, tid = threadIdx.x;
  const int tk = tok[b];
  short* rh = xh_hi + (long)b * KT_;
  short* rl = xh_lo + (long)b * KT_;
  const float* e = embed + (long)tk * E_;
  for (int i = tid; i < E_; i += 256) split1(e[i], &rh[i], &rl[i]);
  for (int i = tid; i < D_; i += 256) split1(global_[(long)b * D_ + i], &rh[E_ + i], &rl[E_ + i]);
  for (int i = tid; i < H_; i += 256) { rh[ED_ + i] = h_hi[(long)b * H_ + i]; rl[ED_ + i] = h_lo[(long)b * H_ + i]; }
}

__global__ __launch_bounds__(256)
void lstm_reduce_k(const float* __restrict__ gp, const float* __restrict__ b_ih,
                   const float* __restrict__ b_hh, float* __restrict__ h, float* __restrict__ m,
                   short* __restrict__ h_hi, short* __restrict__ h_lo)
{
  const int idx = blockIdx.x * 256 + threadIdx.x;
  const int b = idx >> 11, n = idx & (H_ - 1);
  float g[4];
#pragma unroll
  for (int j = 0; j < 4; ++j) {
    float s = b_ih[j*H_ + n] + b_hh[j*H_ + n];
#pragma unroll
    for (int sl = 0; sl < 8; ++sl) s += gp[((long)sl * B_ + b) * H4_ + j*H_ + n];
    g[j] = s;
  }
  const float si = 1.f / (1.f + expf(-g[0]));
  const float sf = 1.f / (1.f + expf(-g[1]));
  const float gg = tanhf(g[2]);
  const float so = 1.f / (1.f + expf(-g[3]));
  const float mn = sf * m[idx] + si * gg;
  const float hn = so * tanhf(mn);
  m[idx] = mn; h[idx] = hn;
  split1(hn, &h_hi[idx], &h_lo[idx]);
}

__global__ __launch_bounds__(256)
void attn_k(const float* __restrict__ sp_proj, const float* __restrict__ hgp,
            const float* __restrict__ w_h, const float* __restrict__ spatial,
            const float* __restrict__ h,
            short* __restrict__ a_hi, short* __restrict__ a_lo)
{
  const int b = blockIdx.x, half = blockIdx.y, tid = threadIdx.x;
  const int lane = tid & 63, wv = tid >> 6;
  __shared__ float hgs[KA_];
  __shared__ float whs[KA_];
  __shared__ float zs[L_];
  __shared__ float alph[L_];
  for (int i = tid; i < KA_; i += 256) {
    float s = 0.f;
#pragma unroll
    for (int sl = 0; sl < 16; ++sl) s += hgp[((long)sl * B_ + b) * KA_ + i];
    hgs[i] = s; whs[i] = w_h[i];
  }
  __syncthreads();
  for (int l = wv; l < L_; l += 4) {
    const float* sp = sp_proj + ((long)b * L_ + l) * KA_;
    float s = 0.f;
    for (int k = lane; k < KA_; k += 64) s += whs[k] * tanhf(sp[k] + hgs[k]);
#pragma unroll
    for (int off = 32; off > 0; off >>= 1) s += __shfl_down(s, off);
    if (lane == 0) zs[l] = s;
  }
  __syncthreads();
  if (wv == 0) {
    float v = (lane < L_) ? zs[lane] : -INFINITY;
    float mx = v;
#pragma unroll
    for (int off = 32; off > 0; off >>= 1) mx = fmaxf(mx, __shfl_xor(mx, off));
    float e = (lane < L_) ? expf(v - mx) : 0.f;
    float sum = e;
#pragma unroll
    for (int off = 32; off > 0; off >>= 1) sum += __shfl_xor(sum, off);
    if (lane < L_) alph[lane] = e / sum;
  }
  __syncthreads();
  const int d4 = half * 256 + tid;
  const float4* h4 = (const float4*)h;
  const float4* sp4 = (const float4*)spatial;
  float4 acc = h4[(long)b * 512 + d4];
#pragma unroll 7
  for (int l = 0; l < L_; ++l) {
    const float w = alph[l];
    const float4 v = sp4[((long)b * L_ + l) * 512 + d4];
    acc.x = fmaf(w, v.x, acc.x); acc.y = fmaf(w, v.y, acc.y);
    acc.z = fmaf(w, v.z, acc.z); acc.w = fmaf(w, v.w, acc.w);
  }
  short4 hv, lv;
  split1(acc.x, &hv.x, &lv.x); split1(acc.y, &hv.y, &lv.y);
  split1(acc.z, &hv.z, &lv.z); split1(acc.w, &hv.w, &lv.w);
  *(short4*)&a_hi[(long)b * D_ + d4*4] = hv;
  *(short4*)&a_lo[(long)b * D_ + d4*4] = lv;
}

// reduce logits partials (S slices, padded VP_) + bias -> out, argmax,
// and (GATHER) build next step's xh planes.
template<int S, bool GATHER>
__global__ __launch_bounds__(256)
void logits_argmax_k(const float* __restrict__ lp, const float* __restrict__ bias,
                     float* __restrict__ outL, int* __restrict__ tok,
                     float* __restrict__ tokout,
                     const float* __restrict__ embed,
                     const short* __restrict__ g_hi, const short* __restrict__ g_lo,
                     const short* __restrict__ h_hi, const short* __restrict__ h_lo,
                     short* __restrict__ xh_hi, short* __restrict__ xh_lo)
{
  const int b = blockIdx.x, tid = threadIdx.x;
  float bv = -INFINITY; int bi = 0x7fffffff;
  for (int j = tid; j < V_; j += 256) {
    float v = bias[j];
#pragma unroll
    for (int sl = 0; sl < S; ++sl) v += lp[((long)sl * B_ + b) * VP_ + j];
    outL[(long)b * (T_*V_) + j] = v;
    if (v > bv) { bv = v; bi = j; }
  }
  __shared__ float sv[256];
  __shared__ int   si[256];
  sv[tid] = bv; si[tid] = bi;
  __syncthreads();
  for (int s = 128; s > 0; s >>= 1) {
    if (tid < s) {
      const float ov = sv[tid + s]; const int oi = si[tid + s];
      if (ov > sv[tid] || (ov == sv[tid] && oi < si[tid])) { sv[tid] = ov; si[tid] = oi; }
    }
    __syncthreads();
  }
  if (tid == 0) { tok[b] = si[0]; tokout[(long)b * T_] = (float)si[0]; }
  if (GATHER) {
    __syncthreads();
    const int tk = si[0];
    short* rh = xh_hi + (long)b * KT_;
    short* rl = xh_lo + (long)b * KT_;
    const float* e = embed + (long)tk * E_;
    for (int i = tid; i < E_; i += 256) split1(e[i], &rh[i], &rl[i]);
    for (int i = tid; i < D_; i += 256) { rh[E_+i] = g_hi[(long)b*D_ + i]; rl[E_+i] = g_lo[(long)b*D_ + i]; }
    for (int i = tid; i < H_; i += 256) { rh[ED_+i] = h_hi[(long)b*H_ + i]; rl[ED_+i] = h_lo[(long)b*H_ + i]; }
  }
}

// ============ host ============
extern "C" void kernel_launch(void* const* d_in, const int* in_sizes, int n_in,
                              void* d_out, int out_size, void* d_ws, size_t ws_size,
                              hipStream_t stream)
{
  const float* spatial  = (const float*)d_in[0];
  const float* global_  = (const float*)d_in[1];
  const float* embed    = (const float*)d_in[2];
  const float* W_ih     = (const float*)d_in[3];
  const float* W_hh     = (const float*)d_in[4];
  const float* b_ih     = (const float*)d_in[5];
  const float* b_hh     = (const float*)d_in[6];
  const float* W_v      = (const float*)d_in[7];
  const float* W_g      = (const float*)d_in[8];
  const float* w_h      = (const float*)d_in[9];
  const float* W_p_w    = (const float*)d_in[10];
  const float* W_p_b    = (const float*)d_in[11];
  const float* W_init_h = (const float*)d_in[12];
  const float* W_init_m = (const float*)d_in[13];
  float* out = (float*)d_out;
  float* tokout = out + (long)B_ * T_ * V_;

  char* base = (char*)d_ws;
  const size_t NEED_PRE = 304087808;
  const size_t NEED_FB  = 62390784;
  if (ws_size < NEED_FB) return;

  if (ws_size >= NEED_PRE) {
    // ---- main layout ----
    float* sp    = (float*)(base + 0);           // 12,845,056
    float* h     = (float*)(base + 12845056);    //  1,048,576
    float* m     = (float*)(base + 13893632);    //  1,048,576
    short* h_hi  = (short*)(base + 14942208);    //    524,288
    short* h_lo  = (short*)(base + 15466496);
    short* a_hi  = (short*)(base + 15990784);
    short* a_lo  = (short*)(base + 16515072);
    short* xh_hi = (short*)(base + 17039360);    //  1,179,648
    short* xh_lo = (short*)(base + 18219008);
    short* g_hi  = (short*)(base + 19398656);    //    524,288
    short* g_lo  = (short*)(base + 19922944);
    int*   tok   = (int*)  (base + 20447232);    //        512
    float* arena = (float*)(base + 20447744);    // 41,418,752
    short* Wcat_hi = (short*)(base + 61866496);  // 75,497,472
    short* Wcat_lo = (short*)(base + 137363968);
    short* Wp_hi   = (short*)(base + 212861440); // 41,418,752
    short* Wp_lo   = (short*)(base + 254280192);
    short* WvT_hi  = (short*)(base + 295698944); //  2,097,152
    short* WvT_lo  = (short*)(base + 297796096);
    short* WgT_hi  = (short*)(base + 299893248);
    short* WgT_lo  = (short*)(base + 301990400);

    init_tok_k<<<1, 128, 0, stream>>>(tok);

    // sp = spatial @ W_v : split A and W to planes, S=4, reduce
    split_t_k<<<dim3(KA_/64, D_/64), 256, 0, stream>>>(W_v, D_, KA_, WvT_hi, WvT_lo);
    short* spA_hi = Wp_hi;                         // staged in Wp region
    short* spA_lo = (short*)((char*)Wp_hi + 25690112);
    split_plane_k<<<12544, 256, 0, stream>>>(spatial, (long)B_*L_*D_, spA_hi, spA_lo);
    float* sppart = (float*)Wcat_hi;               // staged in Wcat region
    gemm_ws<<<dim3(4, 4, 49), 256, 0, stream>>>(
        spA_hi, spA_lo, D_, WvT_hi, WvT_lo, D_, sppart, B_*L_, KA_, 512);
    reduce_sp_k<<<3136, 256, 0, stream>>>((const float4*)sppart, (float4*)sp);

    // weight planes
    split_t_k<<<dim3(KA_/64, H_/64), 256, 0, stream>>>(W_g, H_, KA_, WgT_hi, WgT_lo);
    split_nt_k<<<dim3(3, H4_), 256, 0, stream>>>(W_ih, H4_, ED_, Wcat_hi, Wcat_lo, KT_, 0);
    split_nt_k<<<dim3(2, H4_), 256, 0, stream>>>(W_hh, H4_, H_,  Wcat_hi, Wcat_lo, KT_, ED_);
    split_nt_k<<<dim3(2, VP_), 256, 0, stream>>>(W_p_w, V_, H_,  Wp_hi,   Wp_lo,   H_, 0);
    split_plane_k<<<256, 256, 0, stream>>>(global_, (long)B_*D_, g_hi, g_lo);

    // h0/m0
    {
      short* WTh = (short*)arena;
      short* WTl = (short*)((char*)arena + 8388608);
      float* prt = (float*)((char*)arena + 16777216);   // 16 x 128 x 2048 f32
      split_t_k<<<dim3(H_/64, D_/64), 256, 0, stream>>>(W_init_h, D_, H_, WTh, WTl);
      gemm_ws<<<dim3(16, 16, 1), 256, 0, stream>>>(
          g_hi, g_lo, D_, WTh, WTl, D_, prt, B_, H_, 128);
      reduce_tanh_k<<<(B_*H_)/256, 256, 0, stream>>>(prt, 16, h, h_hi, h_lo);
      split_t_k<<<dim3(H_/64, D_/64), 256, 0, stream>>>(W_init_m, D_, H_, WTh, WTl);
      gemm_ws<<<dim3(16, 16, 1), 256, 0, stream>>>(
          g_hi, g_lo, D_, WTh, WTl, D_, prt, B_, H_, 128);
      reduce_tanh_k<<<(B_*H_)/256, 256, 0, stream>>>(prt, 16, m, nullptr, nullptr);
    }

    gather_xh_k<<<B_, 256, 0, stream>>>(embed, global_, h_hi, h_lo, tok, xh_hi, xh_lo);

    for (int t = 0; t < T_; ++t) {
      // gates: S=8, k_len=576
      gemm_ws<<<dim3(64, 8, 1), 256, 0, stream>>>(
          xh_hi, xh_lo, KT_, Wcat_hi, Wcat_lo, KT_, arena, B_, H4_, 576);
      lstm_reduce_k<<<(B_*H_)/256, 256, 0, stream>>>(arena, b_ih, b_hh, h, m, h_hi, h_lo);
      // hg: S=16, k_len=128
      gemm_ws<<<dim3(4, 16, 1), 256, 0, stream>>>(
          h_hi, h_lo, H_, WgT_hi, WgT_lo, H_, arena, B_, KA_, 128);
      attn_k<<<dim3(B_, 2), 256, 0, stream>>>(sp, arena, w_h, spatial, h, a_hi, a_lo);
      // logits: S=8, k_len=256
      gemm_ws<<<dim3(79, 8, 1), 256, 0, stream>>>(
          a_hi, a_lo, H_, Wp_hi, Wp_lo, H_, arena, B_, VP_, 256);
      logits_argmax_k<8,true><<<B_, 256, 0, stream>>>(
          arena, W_p_b, out + (long)t * V_, tok, tokout + t,
          embed, g_hi, g_lo, h_hi, h_lo, xh_hi, xh_lo);
    }
  } else {
    // -------- fallback (R3 layout): fp32 weights, on-the-fly split --------
    float* sp    = (float*)(base + 0);
    float* WvTf  = (float*)(base + 12845056);
    float* WgTf  = (float*)(base + 17039360);
    float* h     = (float*)(base + 21233664);
    float* m     = (float*)(base + 22282240);
    short* h_hi  = (short*)(base + 24379392);
    short* h_lo  = (short*)(base + 24903680);
    short* a_hi  = (short*)(base + 25427968);
    short* a_lo  = (short*)(base + 25952256);
    short* xh_hi = (short*)(base + 26476544);
    short* xh_lo = (short*)(base + 27656192);
    int*   tok   = (int*)  (base + 28835840);
    float* arena = (float*)(base + 28836352);

    init_tok_k<<<1, 128, 0, stream>>>(tok);
    transpose_f32<<<dim3(KA_/64, D_/64), 256, 0, stream>>>(W_v, D_, KA_, WvTf);
    gemm_mfma<true><<<dim3(4, 1, 49), 256, 0, stream>>>(
        spatial, nullptr, D_, WvTf, D_, nullptr, 0, 1<<30, sp, B_*L_, KA_, KA_, D_);
    transpose_f32<<<dim3(KA_/64, H_/64), 256, 0, stream>>>(W_g, H_, KA_, WgTf);
    {
      float* WT  = arena;
      float* prt = (float*)((char*)arena + 16777216);
      transpose_f32<<<dim3(H_/64, D_/64), 256, 0, stream>>>(W_init_h, D_, H_, WT);
      gemm_mfma<true><<<dim3(16, 4, 1), 256, 0, stream>>>(
          global_, nullptr, D_, WT, D_, nullptr, 0, 1<<30, prt, B_, H_, H_, 512);
      reduce_tanh_k<<<(B_*H_)/256, 256, 0, stream>>>(prt, 4, h, h_hi, h_lo);
      transpose_f32<<<dim3(H_/64, D_/64), 256, 0, stream>>>(W_init_m, D_, H_, WT);
      gemm_mfma<true><<<dim3(16, 4, 1), 256, 0, stream>>>(
          global_, nullptr, D_, WT, D_, nullptr, 0, 1<<30, prt, B_, H_, H_, 512);
      reduce_tanh_k<<<(B_*H_)/256, 256, 0, stream>>>(prt, 4, m, nullptr, nullptr);
    }
    for (int t = 0; t < T_; ++t) {
      gather_xh_k<<<B_, 256, 0, stream>>>(embed, global_, h_hi, h_lo, tok, xh_hi, xh_lo);
      gemm_mfma<false><<<dim3(64, 8, 1), 256, 0, stream>>>(
          xh_hi, xh_lo, KT_, W_ih, ED_, W_hh, H_, ED_, arena, B_, H4_, H4_, 576);
      lstm_reduce_k<<<(B_*H_)/256, 256, 0, stream>>>(arena, b_ih, b_hh, h, m, h_hi, h_lo);
      gemm_mfma<false><<<dim3(4, 16, 1), 256, 0, stream>>>(
          h_hi, h_lo, H_, WgTf, H_, nullptr, 0, 1<<30, arena, B_, KA_, KA_, 128);
      attn_k<<<dim3(B_, 2), 256, 0, stream>>>(sp, arena, w_h, spatial, h, a_hi, a_lo);
      gemm_mfma<false><<<dim3(79, 4, 1), 256, 0, stream>>>(
          a_hi, a_lo, H_, W_p_w, H_, nullptr, 0, 1<<30, arena, B_, VP_, V_, 512);
      logits_argmax_k<4,false><<<B_, 256, 0, stream>>>(
          arena, W_p_b, out + (long)t * V_, tok, tokout + t,
          nullptr, nullptr, nullptr, nullptr, nullptr, nullptr, nullptr);
    }
  }
}